// Round 1
// baseline (422.610 us; speedup 1.0000x reference)
//
#include <hip/hip_runtime.h>
#include <hip/hip_bf16.h>

#define HH 128
#define WW 128
#define CC 80
#define HW (HH * WW)
#define BB 32
#define TOPK 100
#define TROWS 8
#define NTHREADS 256
#define SCORE_THR 0.3f
#define NMS_IOU 0.3f

// ---------------------------------------------------------------------------
// Kernel A: per-pixel peak-NMS + cross-channel max/argmax.
// Grid: BB * (HH/TROWS) = 32*16 = 512 blocks, 256 threads.
// Each block: one batch, 8-row stripe. Loops over 80 channels with a
// double-buffered 10x128 LDS tile (1.25x read amplification).
// ---------------------------------------------------------------------------
__global__ __launch_bounds__(NTHREADS, 2)
void heat_reduce(const float* __restrict__ hm,
                 float* __restrict__ scores,
                 unsigned char* __restrict__ clsout) {
    const int tile = blockIdx.x & 15;     // 16 stripes per batch
    const int b    = blockIdx.x >> 4;
    const int y0   = tile * TROWS;
    const int tid  = threadIdx.x;
    const int x    = tid & 127;
    const int h    = tid >> 7;            // 0/1: which 4-row half this thread owns

    __shared__ float tileS[2][TROWS + 2][WW];

    const float NEG = -1e30f;

    float conf[4] = {0.f, 0.f, 0.f, 0.f};
    int   cls[4]  = {0, 0, 0, 0};

    auto load = [&](int c, int buf) {
        const float* base = hm + ((size_t)(b * CC + c) * HH) * WW;
        // 10 rows * 128 floats = 320 float4
        for (int i = tid; i < 320; i += NTHREADS) {
            int row = i >> 5;             // 0..9
            int xc  = (i & 31) << 2;      // 0,4,...,124
            int y   = y0 - 1 + row;
            float4 v;
            if (y < 0 || y >= HH) {
                v = make_float4(NEG, NEG, NEG, NEG);
            } else {
                v = *(const float4*)(base + (size_t)y * WW + xc);
            }
            *(float4*)&tileS[buf][row][xc] = v;
        }
    };

    load(0, 0);
    __syncthreads();

    for (int c = 0; c < CC; ++c) {
        const int bb = c & 1;
        if (c + 1 < CC) load(c + 1, bb ^ 1);

        // Thread owns local rows h*4 + r (r=0..3); tile row = local + 1.
        // Separable 3x3 max: row-max of 6 tile rows (h*4 .. h*4+5).
        float rmax[6], center[6];
#pragma unroll
        for (int k = 0; k < 6; ++k) {
            int tr  = h * 4 + k;
            float l = (x > 0)   ? tileS[bb][tr][x - 1] : NEG;
            float m =             tileS[bb][tr][x];
            float r = (x < 127) ? tileS[bb][tr][x + 1] : NEG;
            center[k] = m;
            rmax[k]   = fmaxf(fmaxf(l, m), r);
        }
#pragma unroll
        for (int r = 0; r < 4; ++r) {
            float val  = center[r + 1];
            float pool = fmaxf(fmaxf(rmax[r], rmax[r + 1]), rmax[r + 2]);
            float heat = (val == pool) ? val : 0.0f;
            if (heat > conf[r]) { conf[r] = heat; cls[r] = c; }
        }
        __syncthreads();
    }

#pragma unroll
    for (int r = 0; r < 4; ++r) {
        int y = y0 + h * 4 + r;
        size_t o = (size_t)b * HW + (size_t)y * WW + x;
        float s = (conf[r] > SCORE_THR) ? conf[r] : 0.0f;
        scores[o] = s;
        clsout[o] = (unsigned char)cls[r];
    }
}

// ---------------------------------------------------------------------------
// Kernel B: per-batch exact top-100 (radix select + bitonic sort with
// lower-index-first tie break), greedy per-class NMS, box decode + output.
// Grid: 32 blocks (one per batch), 256 threads.
// ---------------------------------------------------------------------------
#define BUF 512

__global__ __launch_bounds__(NTHREADS)
void select_nms(const float* __restrict__ scores,
                const unsigned char* __restrict__ clsin,
                const float* __restrict__ wh,
                const float* __restrict__ offset,
                float* __restrict__ out) {
    const int b   = blockIdx.x;
    const int tid = threadIdx.x;
    const float* s = scores + (size_t)b * HW;

    __shared__ unsigned int hist[256];
    __shared__ unsigned int sPrefix, sNeed, sCnt;
    __shared__ unsigned long long keys[BUF];

    // ---- radix select: find bit pattern of the 100th-largest score ----
    if (tid == 0) { sNeed = TOPK; sPrefix = 0; }

    for (int shift = 24; shift >= 0; shift -= 8) {
        hist[tid] = 0;
        __syncthreads();
        unsigned pfx = sPrefix;
        for (int i = tid; i < HW; i += NTHREADS) {
            unsigned u = __float_as_uint(s[i]);
            unsigned hi = (shift == 24) ? 0u : (u >> (shift + 8));
            if (hi == pfx)
                atomicAdd(&hist[(u >> shift) & 255u], 1u);
        }
        __syncthreads();
        if (tid == 0) {
            unsigned need = sNeed;
            unsigned cum = 0;
            int k = 255;
            for (; k >= 0; --k) {
                if (cum + hist[k] >= need) break;
                cum += hist[k];
            }
            if (k < 0) k = 0;  // defensive; cannot happen (total >= need)
            sPrefix = (pfx << 8) | (unsigned)k;
            sNeed = need - cum;
        }
        __syncthreads();
    }
    const unsigned Vbits = sPrefix;  // exact bits of 100th-largest score

    // ---- compact all candidates with score >= V (and > threshold) ----
    if (tid == 0) sCnt = 0;
    __syncthreads();
    for (int i = tid; i < HW; i += NTHREADS) {
        float sv = s[i];
        unsigned u = __float_as_uint(sv);
        if (u >= Vbits && sv > SCORE_THR) {
            unsigned pos = atomicAdd(&sCnt, 1u);
            if (pos < BUF)
                keys[pos] = ((unsigned long long)u << 32) |
                            (unsigned)(HW - 1 - i);   // tie: lower index first
        }
    }
    __syncthreads();
    int cnt = (int)sCnt;
    if (cnt > BUF) cnt = BUF;
    for (int i = tid; i < BUF; i += NTHREADS)
        if (i >= cnt) keys[i] = 0ull;
    __syncthreads();

    // ---- bitonic sort, descending, 512 u64 keys ----
    for (int k = 2; k <= BUF; k <<= 1) {
        for (int j = k >> 1; j > 0; j >>= 1) {
            for (int i = tid; i < BUF; i += NTHREADS) {
                int p = i ^ j;
                if (p > i) {
                    unsigned long long a = keys[i], bb2 = keys[p];
                    bool asc_seg = ((i & k) != 0);     // descending overall
                    bool swap = asc_seg ? (a > bb2) : (a < bb2);
                    if (swap) { keys[i] = bb2; keys[p] = a; }
                }
            }
            __syncthreads();
        }
    }

    // ---- gather top-100 candidate data ----
    __shared__ float bx[TOPK][4];
    __shared__ float barea[TOPK];
    __shared__ float bsc[TOPK];
    __shared__ int   bcls[TOPK];
    __shared__ int   keep[TOPK];

    if (tid < TOPK) {
        unsigned long long kk = keys[tid];
        float sc = __uint_as_float((unsigned)(kk >> 32));
        int   i  = HW - 1 - (int)(kk & 0xFFFFFFFFull);
        int   y  = (i >> 7) & 127;
        int   x  = i & 127;
        size_t base = (size_t)b * 2 * HW + (size_t)y * WW + x;
        float ox = offset[base];
        float oy = offset[base + HW];
        float w  = wh[base];
        float hh = wh[base + HW];
        float cx = (float)x + ox;
        float cy = (float)y + oy;
        float x1 = (cx - w  * 0.5f) * (1.0f / 128.0f);
        float y1 = (cy - hh * 0.5f) * (1.0f / 128.0f);
        float x2 = (cx + w  * 0.5f) * (1.0f / 128.0f);
        float y2 = (cy + hh * 0.5f) * (1.0f / 128.0f);
        bx[tid][0] = x1; bx[tid][1] = y1; bx[tid][2] = x2; bx[tid][3] = y2;
        barea[tid] = (x2 - x1) * (y2 - y1);
        bsc[tid]   = sc;
        bcls[tid]  = (int)clsin[(size_t)b * HW + i];
        keep[tid]  = (sc > SCORE_THR) ? 1 : 0;
    }
    __syncthreads();

    // ---- greedy per-class NMS (sequential over score-sorted candidates) ----
    for (int i2 = 0; i2 < TOPK; ++i2) {
        if (keep[i2]) {
            if (tid > i2 && tid < TOPK && keep[tid] && bcls[tid] == bcls[i2]) {
                float lx = fmaxf(bx[tid][0], bx[i2][0]);
                float ly = fmaxf(bx[tid][1], bx[i2][1]);
                float rx = fminf(bx[tid][2], bx[i2][2]);
                float ry = fminf(bx[tid][3], bx[i2][3]);
                float iw = fmaxf(rx - lx, 0.0f);
                float ih = fmaxf(ry - ly, 0.0f);
                float inter = iw * ih;
                float iou = inter / (barea[tid] + barea[i2] - inter + 1e-9f);
                if (iou > NMS_IOU) keep[tid] = 0;
            }
        }
        __syncthreads();
    }

    // ---- write output [B, 100, 6]; zero non-kept rows (d_out is poisoned) ----
    for (int t = tid; t < TOPK * 6; t += NTHREADS) {
        int j = t / 6, comp = t - j * 6;
        float v = 0.0f;
        if (keep[j]) {
            if (comp < 4)      v = bx[j][comp] * 512.0f;
            else if (comp == 4) v = bsc[j];
            else               v = (float)bcls[j];
        }
        out[(size_t)b * (TOPK * 6) + t] = v;
    }
}

extern "C" void kernel_launch(void* const* d_in, const int* in_sizes, int n_in,
                              void* d_out, int out_size, void* d_ws, size_t ws_size,
                              hipStream_t stream) {
    const float* hm     = (const float*)d_in[0];
    const float* wh     = (const float*)d_in[1];
    const float* offset = (const float*)d_in[2];
    float* out = (float*)d_out;

    float* scores = (float*)d_ws;                                   // 2 MB
    unsigned char* clsb = (unsigned char*)d_ws + (size_t)BB * HW * 4; // 0.5 MB

    heat_reduce<<<BB * (HH / TROWS), NTHREADS, 0, stream>>>(hm, scores, clsb);
    select_nms<<<BB, NTHREADS, 0, stream>>>(scores, clsb, wh, offset, out);
}

// Round 2
// 300.044 us; speedup vs baseline: 1.4085x; 1.4085x over previous
//
#include <hip/hip_runtime.h>
#include <hip/hip_bf16.h>
#include <stdint.h>

#define HH 128
#define WW 128
#define CC 80
#define HW (HH * WW)
#define BB 32
#define TOPK 100
#define TROWS 8
#define NTHREADS 256
#define SCORE_THR 0.3f
#define NMS_IOU 0.3f
#define BUF 512
// smallest uint bit pattern with float > 0.3f  (bits(0.3f)=0x3E99999A)
#define MINT 0x3E99999Bu

// ---------------------------------------------------------------------------
// async 16B global->LDS (CK idiom for address-space casts)
// ---------------------------------------------------------------------------
__device__ __forceinline__ void async_load16(const float* gp, const float* lp) {
    auto g = (const __attribute__((address_space(1))) void*)(uintptr_t)gp;
    auto l = (__attribute__((address_space(3))) void*)(uint32_t)(uintptr_t)lp;
    __builtin_amdgcn_global_load_lds(g, l, 16, 0, 0);
}

// ---------------------------------------------------------------------------
// Kernel A: peak-NMS + per-group channel max/argmax partials.
// Grid: BB * 16 * G blocks (G channel groups), 256 threads.
// Clamp padding == -inf padding for 3x3 max pool (center row duplicated into
// halo never changes the max), so no boundary branches and uniform async load.
// ---------------------------------------------------------------------------
template <int G>
__global__ __launch_bounds__(NTHREADS, 8)
void heat_reduce(const float* __restrict__ hm,
                 float* __restrict__ conf_out,
                 unsigned char* __restrict__ cls_out) {
    constexpr int CPG = CC / G;
    const int g      = blockIdx.x % G;
    const int stripe = (blockIdx.x / G) & 15;
    const int b      = blockIdx.x / (16 * G);
    const int y0     = stripe * TROWS;
    const int tid    = threadIdx.x;
    const int lane   = tid & 63;
    const int wv     = tid >> 6;
    const int x      = tid & 127;
    const int h      = tid >> 7;          // 0/1: 4-row half
    const int c0     = g * CPG;

    __shared__ float tileS[2][(TROWS + 2) * WW];   // 2 x 5KB

    auto load = [&](int c, int buf) {
        const float* base = hm + (size_t)(b * CC + c) * HW;
        // 10 rows * 128 floats = 320 float4 = 5 chunks of 64 lanes x 16B
        for (int chunk = wv; chunk < 5; chunk += 4) {
            int e    = chunk * 64 + lane;     // float4 id
            int row  = e >> 5;                // 0..9
            int col  = (e & 31) << 2;         // 0..124
            int y    = y0 - 1 + row;
            y = min(max(y, 0), HH - 1);       // clamp halo
            async_load16(base + (size_t)y * WW + col,
                         &tileS[buf][chunk * 256]);
        }
    };

    float conf[4] = {0.f, 0.f, 0.f, 0.f};
    int   cls[4]  = {c0, c0, c0, c0};

    const int xl = (x > 0) ? x - 1 : x;       // clamp == -inf for max-pool
    const int xr = (x < WW - 1) ? x + 1 : x;

    load(c0, 0);
    __syncthreads();

    for (int cc = 0; cc < CPG; ++cc) {
        const int c  = c0 + cc;
        const int bb = cc & 1;
        if (cc + 1 < CPG) load(c + 1, bb ^ 1);

        float rmax[6], center[6];
#pragma unroll
        for (int k = 0; k < 6; ++k) {
            const float* row = &tileS[bb][(h * 4 + k) * WW];
            float l = row[xl], m = row[x], r = row[xr];
            center[k] = m;
            rmax[k]   = fmaxf(fmaxf(l, m), r);
        }
#pragma unroll
        for (int r = 0; r < 4; ++r) {
            float val  = center[r + 1];
            float pool = fmaxf(fmaxf(rmax[r], rmax[r + 1]), rmax[r + 2]);
            float heat = (val == pool) ? val : 0.0f;
            if (heat > conf[r]) { conf[r] = heat; cls[r] = c; }
        }
        __syncthreads();
    }

#pragma unroll
    for (int r = 0; r < 4; ++r) {
        int y = y0 + h * 4 + r;
        size_t idx = (size_t)b * HW + (size_t)y * WW + x;
        conf_out[idx * G + g] = conf[r];
        cls_out[idx * G + g]  = (unsigned char)cls[r];
    }
}

// ---------------------------------------------------------------------------
// Kernel B: merge partials, exact top-100 (register-resident binary search on
// score bits; zero atomic-histograms), bitonic sort w/ index tie-break,
// wave0-resident greedy per-class NMS, decode + output.
// Grid: 32 blocks (one per batch), 256 threads.
// ---------------------------------------------------------------------------
template <int G>
__global__ __launch_bounds__(NTHREADS, 1)
void select_nms(const float* __restrict__ conf_part,
                const unsigned char* __restrict__ cls_part,
                const float* __restrict__ wh,
                const float* __restrict__ offset,
                float* __restrict__ out) {
    const int b    = blockIdx.x;
    const int tid  = threadIdx.x;
    const int lane = tid & 63;
    const int wid  = tid >> 6;
    constexpr int VALS = HW / NTHREADS;   // 64

    __shared__ int wsum[4];
    __shared__ unsigned int sCnt;
    __shared__ unsigned long long keys[BUF];

    // ---- load + merge partials into registers (thresholded score bits) ----
    unsigned u[VALS];
#pragma unroll
    for (int k = 0; k < VALS; ++k) {
        int i = k * NTHREADS + tid;
        float best;
        if constexpr (G == 4) {
            float4 cf = *(const float4*)&conf_part[(size_t)(b * HW + i) * 4];
            best = cf.x;
            if (cf.y > best) best = cf.y;
            if (cf.z > best) best = cf.z;
            if (cf.w > best) best = cf.w;
        } else {
            best = conf_part[(size_t)b * HW + i];
        }
        u[k] = (best > SCORE_THR) ? __float_as_uint(best) : 0u;
    }

    auto blockCount = [&](unsigned T) -> int {
        int c = 0;
#pragma unroll
        for (int k = 0; k < VALS; ++k) c += (u[k] >= T);
        for (int o = 32; o > 0; o >>= 1) c += __shfl_down(c, o, 64);
        if (lane == 0) wsum[wid] = c;
        __syncthreads();
        int tot = wsum[0] + wsum[1] + wsum[2] + wsum[3];
        __syncthreads();
        return tot;
    };

    // ---- binary search on uint bits for the 100th-largest score ----
    unsigned V;
    {
        unsigned lo = MINT, hi = 0x3F800001u;   // scores in [0,1)
        int cl = blockCount(lo);
        if (cl < TOPK) {
            V = lo;
        } else {
            while (hi - lo > 1u) {
                unsigned mid = lo + ((hi - lo) >> 1);
                if (blockCount(mid) >= TOPK) lo = mid; else hi = mid;
            }
            V = lo;
        }
    }

    // ---- compact candidates (u >= V) ----
    if (tid == 0) sCnt = 0;
    for (int i = tid; i < BUF; i += NTHREADS) keys[i] = 0ull;
    __syncthreads();
#pragma unroll
    for (int k = 0; k < VALS; ++k) {
        if (u[k] >= V) {
            int i = k * NTHREADS + tid;
            unsigned pos = atomicAdd(&sCnt, 1u);
            if (pos < BUF)
                keys[pos] = ((unsigned long long)u[k] << 32) |
                            (unsigned)(HW - 1 - i);   // tie: lower index first
        }
    }
    __syncthreads();
    int cnt = (int)sCnt;
    if (cnt > BUF) cnt = BUF;

    // ---- bitonic sort (descending), size = next pow2 >= cnt ----
    int n = 1;
    while (n < cnt) n <<= 1;
    for (int k = 2; k <= n; k <<= 1) {
        for (int j = k >> 1; j > 0; j >>= 1) {
            for (int i = tid; i < n; i += NTHREADS) {
                int p = i ^ j;
                if (p > i) {
                    unsigned long long a = keys[i], bb2 = keys[p];
                    bool asc_seg = ((i & k) != 0);
                    bool sw = asc_seg ? (a > bb2) : (a < bb2);
                    if (sw) { keys[i] = bb2; keys[p] = a; }
                }
            }
            __syncthreads();
        }
    }

    // ---- gather top-100 ----
    __shared__ float bx[TOPK][4];
    __shared__ float barea[TOPK];
    __shared__ float bsc[TOPK];
    __shared__ int   bcls[TOPK];
    __shared__ int   keep[TOPK];

    if (tid < TOPK) {
        unsigned long long kk = keys[tid];
        float sc = __uint_as_float((unsigned)(kk >> 32));
        int   i  = HW - 1 - (int)(kk & 0xFFFFFFFFull);
        int   y  = (i >> 7) & 127;
        int   x  = i & 127;
        // merged class (strict >, group-ascending == global first-index argmax)
        const float*         cp = conf_part + (size_t)(b * HW + i) * G;
        const unsigned char* kp = cls_part  + (size_t)(b * HW + i) * G;
        float bcf = cp[0]; int bc = kp[0];
#pragma unroll
        for (int gg = 1; gg < G; ++gg)
            if (cp[gg] > bcf) { bcf = cp[gg]; bc = kp[gg]; }

        size_t base = (size_t)b * 2 * HW + (size_t)y * WW + x;
        float ox = offset[base];
        float oy = offset[base + HW];
        float w  = wh[base];
        float hh = wh[base + HW];
        float cx = (float)x + ox;
        float cy = (float)y + oy;
        float x1 = (cx - w  * 0.5f) * (1.0f / 128.0f);
        float y1 = (cy - hh * 0.5f) * (1.0f / 128.0f);
        float x2 = (cx + w  * 0.5f) * (1.0f / 128.0f);
        float y2 = (cy + hh * 0.5f) * (1.0f / 128.0f);
        bx[tid][0] = x1; bx[tid][1] = y1; bx[tid][2] = x2; bx[tid][3] = y2;
        barea[tid] = (x2 - x1) * (y2 - y1);
        bsc[tid]   = sc;
        bcls[tid]  = bc;
        keep[tid]  = (sc > SCORE_THR) ? 1 : 0;
    }
    __syncthreads();

    // ---- greedy per-class NMS: single wave, shuffle broadcasts, 0 barriers --
    if (tid < 64) {
        const int A  = tid;
        const int Bq = tid + 64;
        float aX0 = bx[A][0], aY0 = bx[A][1], aX1 = bx[A][2], aY1 = bx[A][3];
        float aAr = barea[A]; int aC = bcls[A]; int kA = keep[A];
        float bX0 = 0, bY0 = 0, bX1 = 0, bY1 = 0, bAr = 0;
        int   bC = -1, kB = 0;
        if (Bq < TOPK) {
            bX0 = bx[Bq][0]; bY0 = bx[Bq][1]; bX1 = bx[Bq][2]; bY1 = bx[Bq][3];
            bAr = barea[Bq]; bC = bcls[Bq]; kB = keep[Bq];
        }
        for (int i = 0; i < TOPK; ++i) {
            int kv    = (i < 64) ? kA : kB;
            int alive = __shfl(kv, i & 63, 64);
            if (alive) {
                float iX0 = bx[i][0], iY0 = bx[i][1];
                float iX1 = bx[i][2], iY1 = bx[i][3];
                float iAr = barea[i]; int iC = bcls[i];
                if (A > i && aC == iC) {
                    float lx = fmaxf(aX0, iX0), ly = fmaxf(aY0, iY0);
                    float rx = fminf(aX1, iX1), ry = fminf(aY1, iY1);
                    float iw = fmaxf(rx - lx, 0.f), ih = fmaxf(ry - ly, 0.f);
                    float inter = iw * ih;
                    float iou = inter / (aAr + iAr - inter + 1e-9f);
                    if (iou > NMS_IOU) kA = 0;
                }
                if (Bq > i && Bq < TOPK && bC == iC) {
                    float lx = fmaxf(bX0, iX0), ly = fmaxf(bY0, iY0);
                    float rx = fminf(bX1, iX1), ry = fminf(bY1, iY1);
                    float iw = fmaxf(rx - lx, 0.f), ih = fmaxf(ry - ly, 0.f);
                    float inter = iw * ih;
                    float iou = inter / (bAr + iAr - inter + 1e-9f);
                    if (iou > NMS_IOU) kB = 0;
                }
            }
        }
        keep[A] = kA;
        if (Bq < TOPK) keep[Bq] = kB;
    }
    __syncthreads();

    // ---- output [B,100,6]; zero non-kept rows (d_out is poisoned) ----
    for (int t = tid; t < TOPK * 6; t += NTHREADS) {
        int j = t / 6, comp = t - j * 6;
        float v = 0.0f;
        if (keep[j]) {
            if (comp < 4)       v = bx[j][comp] * 512.0f;
            else if (comp == 4) v = bsc[j];
            else                v = (float)bcls[j];
        }
        out[(size_t)b * (TOPK * 6) + t] = v;
    }
}

extern "C" void kernel_launch(void* const* d_in, const int* in_sizes, int n_in,
                              void* d_out, int out_size, void* d_ws, size_t ws_size,
                              hipStream_t stream) {
    const float* hm     = (const float*)d_in[0];
    const float* wh     = (const float*)d_in[1];
    const float* offset = (const float*)d_in[2];
    float* out = (float*)d_out;

    const size_t need4 = (size_t)BB * HW * (4 * 4 + 4);   // 10 MB
    if (ws_size >= need4) {
        float* confp = (float*)d_ws;
        unsigned char* clsp = (unsigned char*)d_ws + (size_t)BB * HW * 4 * 4;
        heat_reduce<4><<<BB * 16 * 4, NTHREADS, 0, stream>>>(hm, confp, clsp);
        select_nms<4><<<BB, NTHREADS, 0, stream>>>(confp, clsp, wh, offset, out);
    } else {
        float* confp = (float*)d_ws;
        unsigned char* clsp = (unsigned char*)d_ws + (size_t)BB * HW * 4;
        heat_reduce<1><<<BB * 16 * 1, NTHREADS, 0, stream>>>(hm, confp, clsp);
        select_nms<1><<<BB, NTHREADS, 0, stream>>>(confp, clsp, wh, offset, out);
    }
}

// Round 3
// 297.597 us; speedup vs baseline: 1.4201x; 1.0082x over previous
//
#include <hip/hip_runtime.h>
#include <hip/hip_bf16.h>
#include <stdint.h>

#define HH 128
#define WW 128
#define CC 80
#define HW (HH * WW)
#define BB 32
#define TOPK 100
#define TROWS 8
#define NTHREADS 256
#define SCORE_THR 0.3f
#define NMS_IOU 0.3f
#define BUF 512
// smallest uint bit pattern with float > 0.3f  (bits(0.3f)=0x3E99999A)
#define MINT 0x3E99999Bu

// ---------------------------------------------------------------------------
// async 16B global->LDS
// ---------------------------------------------------------------------------
__device__ __forceinline__ void async_load16(const float* gp, const float* lp) {
    auto g = (const __attribute__((address_space(1))) void*)(uintptr_t)gp;
    auto l = (__attribute__((address_space(3))) void*)(uint32_t)(uintptr_t)lp;
    __builtin_amdgcn_global_load_lds(g, l, 16, 0, 0);
}

// ---------------------------------------------------------------------------
// Kernel A: peak-NMS + per-group channel max/argmax partials.
// Grid: BB * 16 * G blocks, 256 threads. TWO channels per barrier iteration,
// 4 LDS tile buffers (20 KB/block = exactly 8 blocks/CU): halves barrier
// count and doubles in-flight prefetch bytes (10 KB/block) vs round 2.
// Clamp padding == -inf padding for 3x3 max pool.
// ---------------------------------------------------------------------------
template <int G>
__global__ __launch_bounds__(NTHREADS, 8)
void heat_reduce(const float* __restrict__ hm,
                 float* __restrict__ conf_out,
                 unsigned char* __restrict__ cls_out) {
    constexpr int CPG = CC / G;              // 20 for G=4 (even)
    constexpr int NPAIR = CPG / 2;           // 10
    const int g      = blockIdx.x % G;
    const int stripe = (blockIdx.x / G) & 15;
    const int b      = blockIdx.x / (16 * G);
    const int y0     = stripe * TROWS;
    const int tid    = threadIdx.x;
    const int lane   = tid & 63;
    const int wv     = tid >> 6;
    const int x      = tid & 127;
    const int h      = tid >> 7;             // 0/1: 4-row half
    const int c0     = g * CPG;

    __shared__ float tileS[4][(TROWS + 2) * WW];   // 4 x 5 KB = 20 KB

    // load channel pair (c, c+1) into buffers bufbase, bufbase+1
    auto load_pair = [&](int c, int bufbase) {
        // 2 channels * 5 chunks; chunk = ch*5 + k; 64 lanes x 16B per chunk
        for (int chunk = wv; chunk < 10; chunk += 4) {
            int ch = (chunk >= 5) ? 1 : 0;
            int k  = chunk - ch * 5;
            int e  = k * 64 + lane;          // float4 id within tile
            int row = e >> 5;                // 0..9
            int col = (e & 31) << 2;         // 0..124
            int y = y0 - 1 + row;
            y = min(max(y, 0), HH - 1);      // clamp halo
            const float* base = hm + (size_t)(b * CC + c + ch) * HW;
            async_load16(base + (size_t)y * WW + col,
                         &tileS[bufbase + ch][k * 256]);
        }
    };

    float conf[4] = {0.f, 0.f, 0.f, 0.f};
    int   cls[4]  = {c0, c0, c0, c0};

    const int xl = (x > 0) ? x - 1 : x;      // clamp == -inf for max-pool
    const int xr = (x < WW - 1) ? x + 1 : x;

    auto compute = [&](int c, int buf) {
        float rmax[6], center[6];
#pragma unroll
        for (int k = 0; k < 6; ++k) {
            const float* row = &tileS[buf][(h * 4 + k) * WW];
            float l = row[xl], m = row[x], r = row[xr];
            center[k] = m;
            rmax[k]   = fmaxf(fmaxf(l, m), r);
        }
#pragma unroll
        for (int r = 0; r < 4; ++r) {
            float val  = center[r + 1];
            float pool = fmaxf(fmaxf(rmax[r], rmax[r + 1]), rmax[r + 2]);
            float heat = (val == pool) ? val : 0.0f;
            if (heat > conf[r]) { conf[r] = heat; cls[r] = c; }
        }
    };

    load_pair(c0, 0);
    __syncthreads();

    for (int p = 0; p < NPAIR; ++p) {
        const int bb = (p & 1) * 2;
        if (p + 1 < NPAIR) load_pair(c0 + 2 * (p + 1), ((p + 1) & 1) * 2);
        compute(c0 + 2 * p,     bb);
        compute(c0 + 2 * p + 1, bb + 1);
        __syncthreads();
    }

#pragma unroll
    for (int r = 0; r < 4; ++r) {
        int y = y0 + h * 4 + r;
        size_t idx = (size_t)b * HW + (size_t)y * WW + x;
        conf_out[idx * G + g] = conf[r];
        cls_out[idx * G + g]  = (unsigned char)cls[r];
    }
}

// ---------------------------------------------------------------------------
// Kernel B: merge partials, exact top-100 (register-resident binary search on
// score bits), bitonic sort w/ index tie-break, wave0-resident greedy
// per-class NMS, decode + output. Grid: 32 blocks, 256 threads.
// ---------------------------------------------------------------------------
template <int G>
__global__ __launch_bounds__(NTHREADS, 1)
void select_nms(const float* __restrict__ conf_part,
                const unsigned char* __restrict__ cls_part,
                const float* __restrict__ wh,
                const float* __restrict__ offset,
                float* __restrict__ out) {
    const int b    = blockIdx.x;
    const int tid  = threadIdx.x;
    const int lane = tid & 63;
    const int wid  = tid >> 6;
    constexpr int VALS = HW / NTHREADS;   // 64

    __shared__ int wsum[4];
    __shared__ unsigned int sCnt;
    __shared__ unsigned long long keys[BUF];

    // ---- load + merge partials into registers (thresholded score bits) ----
    unsigned u[VALS];
#pragma unroll
    for (int k = 0; k < VALS; ++k) {
        int i = k * NTHREADS + tid;
        float best;
        if constexpr (G == 4) {
            float4 cf = *(const float4*)&conf_part[(size_t)(b * HW + i) * 4];
            best = cf.x;
            if (cf.y > best) best = cf.y;
            if (cf.z > best) best = cf.z;
            if (cf.w > best) best = cf.w;
        } else {
            best = conf_part[(size_t)b * HW + i];
        }
        u[k] = (best > SCORE_THR) ? __float_as_uint(best) : 0u;
    }

    auto blockCount = [&](unsigned T) -> int {
        int c = 0;
#pragma unroll
        for (int k = 0; k < VALS; ++k) c += (u[k] >= T);
        for (int o = 32; o > 0; o >>= 1) c += __shfl_down(c, o, 64);
        if (lane == 0) wsum[wid] = c;
        __syncthreads();
        int tot = wsum[0] + wsum[1] + wsum[2] + wsum[3];
        __syncthreads();
        return tot;
    };

    // ---- binary search on uint bits for the 100th-largest score ----
    unsigned V;
    {
        unsigned lo = MINT, hi = 0x3F800001u;   // scores in [0,1)
        int cl = blockCount(lo);
        if (cl < TOPK) {
            V = lo;
        } else {
            while (hi - lo > 1u) {
                unsigned mid = lo + ((hi - lo) >> 1);
                if (blockCount(mid) >= TOPK) lo = mid; else hi = mid;
            }
            V = lo;
        }
    }

    // ---- compact candidates (u >= V) ----
    if (tid == 0) sCnt = 0;
    for (int i = tid; i < BUF; i += NTHREADS) keys[i] = 0ull;
    __syncthreads();
#pragma unroll
    for (int k = 0; k < VALS; ++k) {
        if (u[k] >= V) {
            int i = k * NTHREADS + tid;
            unsigned pos = atomicAdd(&sCnt, 1u);
            if (pos < BUF)
                keys[pos] = ((unsigned long long)u[k] << 32) |
                            (unsigned)(HW - 1 - i);   // tie: lower index first
        }
    }
    __syncthreads();
    int cnt = (int)sCnt;
    if (cnt > BUF) cnt = BUF;

    // ---- bitonic sort (descending), size = next pow2 >= cnt ----
    int n = 1;
    while (n < cnt) n <<= 1;
    for (int k = 2; k <= n; k <<= 1) {
        for (int j = k >> 1; j > 0; j >>= 1) {
            for (int i = tid; i < n; i += NTHREADS) {
                int p = i ^ j;
                if (p > i) {
                    unsigned long long a = keys[i], bb2 = keys[p];
                    bool asc_seg = ((i & k) != 0);
                    bool sw = asc_seg ? (a > bb2) : (a < bb2);
                    if (sw) { keys[i] = bb2; keys[p] = a; }
                }
            }
            __syncthreads();
        }
    }

    // ---- gather top-100 ----
    __shared__ float bx[TOPK][4];
    __shared__ float barea[TOPK];
    __shared__ float bsc[TOPK];
    __shared__ int   bcls[TOPK];
    __shared__ int   keep[TOPK];

    if (tid < TOPK) {
        unsigned long long kk = keys[tid];
        float sc = __uint_as_float((unsigned)(kk >> 32));
        int   i  = HW - 1 - (int)(kk & 0xFFFFFFFFull);
        int   y  = (i >> 7) & 127;
        int   x  = i & 127;
        // merged class (strict >, group-ascending == global first-index argmax)
        const float*         cp = conf_part + (size_t)(b * HW + i) * G;
        const unsigned char* kp = cls_part  + (size_t)(b * HW + i) * G;
        float bcf = cp[0]; int bc = kp[0];
#pragma unroll
        for (int gg = 1; gg < G; ++gg)
            if (cp[gg] > bcf) { bcf = cp[gg]; bc = kp[gg]; }

        size_t base = (size_t)b * 2 * HW + (size_t)y * WW + x;
        float ox = offset[base];
        float oy = offset[base + HW];
        float w  = wh[base];
        float hh = wh[base + HW];
        float cx = (float)x + ox;
        float cy = (float)y + oy;
        float x1 = (cx - w  * 0.5f) * (1.0f / 128.0f);
        float y1 = (cy - hh * 0.5f) * (1.0f / 128.0f);
        float x2 = (cx + w  * 0.5f) * (1.0f / 128.0f);
        float y2 = (cy + hh * 0.5f) * (1.0f / 128.0f);
        bx[tid][0] = x1; bx[tid][1] = y1; bx[tid][2] = x2; bx[tid][3] = y2;
        barea[tid] = (x2 - x1) * (y2 - y1);
        bsc[tid]   = sc;
        bcls[tid]  = bc;
        keep[tid]  = (sc > SCORE_THR) ? 1 : 0;
    }
    __syncthreads();

    // ---- greedy per-class NMS: single wave, shuffle broadcasts, 0 barriers --
    if (tid < 64) {
        const int A  = tid;
        const int Bq = tid + 64;
        float aX0 = bx[A][0], aY0 = bx[A][1], aX1 = bx[A][2], aY1 = bx[A][3];
        float aAr = barea[A]; int aC = bcls[A]; int kA = keep[A];
        float bX0 = 0, bY0 = 0, bX1 = 0, bY1 = 0, bAr = 0;
        int   bC = -1, kB = 0;
        if (Bq < TOPK) {
            bX0 = bx[Bq][0]; bY0 = bx[Bq][1]; bX1 = bx[Bq][2]; bY1 = bx[Bq][3];
            bAr = barea[Bq]; bC = bcls[Bq]; kB = keep[Bq];
        }
        for (int i = 0; i < TOPK; ++i) {
            int kv    = (i < 64) ? kA : kB;
            int alive = __shfl(kv, i & 63, 64);
            if (alive) {
                float iX0 = bx[i][0], iY0 = bx[i][1];
                float iX1 = bx[i][2], iY1 = bx[i][3];
                float iAr = barea[i]; int iC = bcls[i];
                if (A > i && aC == iC) {
                    float lx = fmaxf(aX0, iX0), ly = fmaxf(aY0, iY0);
                    float rx = fminf(aX1, iX1), ry = fminf(aY1, iY1);
                    float iw = fmaxf(rx - lx, 0.f), ih = fmaxf(ry - ly, 0.f);
                    float inter = iw * ih;
                    float iou = inter / (aAr + iAr - inter + 1e-9f);
                    if (iou > NMS_IOU) kA = 0;
                }
                if (Bq > i && Bq < TOPK && bC == iC) {
                    float lx = fmaxf(bX0, iX0), ly = fmaxf(bY0, iY0);
                    float rx = fminf(bX1, iX1), ry = fminf(bY1, iY1);
                    float iw = fmaxf(rx - lx, 0.f), ih = fmaxf(ry - ly, 0.f);
                    float inter = iw * ih;
                    float iou = inter / (bAr + iAr - inter + 1e-9f);
                    if (iou > NMS_IOU) kB = 0;
                }
            }
        }
        keep[A] = kA;
        if (Bq < TOPK) keep[Bq] = kB;
    }
    __syncthreads();

    // ---- output [B,100,6]; zero non-kept rows (d_out is poisoned) ----
    for (int t = tid; t < TOPK * 6; t += NTHREADS) {
        int j = t / 6, comp = t - j * 6;
        float v = 0.0f;
        if (keep[j]) {
            if (comp < 4)       v = bx[j][comp] * 512.0f;
            else if (comp == 4) v = bsc[j];
            else                v = (float)bcls[j];
        }
        out[(size_t)b * (TOPK * 6) + t] = v;
    }
}

extern "C" void kernel_launch(void* const* d_in, const int* in_sizes, int n_in,
                              void* d_out, int out_size, void* d_ws, size_t ws_size,
                              hipStream_t stream) {
    const float* hm     = (const float*)d_in[0];
    const float* wh     = (const float*)d_in[1];
    const float* offset = (const float*)d_in[2];
    float* out = (float*)d_out;

    const size_t need4 = (size_t)BB * HW * (4 * 4 + 4);   // 10 MB
    if (ws_size >= need4) {
        float* confp = (float*)d_ws;
        unsigned char* clsp = (unsigned char*)d_ws + (size_t)BB * HW * 4 * 4;
        heat_reduce<4><<<BB * 16 * 4, NTHREADS, 0, stream>>>(hm, confp, clsp);
        select_nms<4><<<BB, NTHREADS, 0, stream>>>(confp, clsp, wh, offset, out);
    } else {
        float* confp = (float*)d_ws;
        unsigned char* clsp = (unsigned char*)d_ws + (size_t)BB * HW * 4;
        heat_reduce<1><<<BB * 16 * 1, NTHREADS, 0, stream>>>(hm, confp, clsp);
        select_nms<1><<<BB, NTHREADS, 0, stream>>>(confp, clsp, wh, offset, out);
    }
}